// Round 1
// baseline (2032.248 us; speedup 1.0000x reference)
//
#include <hip/hip_runtime.h>
#include <cmath>

#define D 1024
#define DFF 4096
#define NHEADS 16
#define DH 64
#define S_CACHE 512
#define SP1 513
#define NB_L 24
#define NR_L 8

// workspace layout (float offsets)
#define WS_H      0         // [2][1024]
#define WS_H2     2048      // [2][1024]
#define WS_QKV    4096      // [4][3][2][1024] = 24576
#define WS_ATTN   28672     // [2][16][9][68]  = 19584
#define WS_OPROJ  48256     // [8][2][1024]    = 16384
#define WS_GU     64640     // [4][2][2][4096] = 65536
#define WS_DOWN   130176    // [16][2][1024]   = 32768
#define WS_SPROJ  162944    // [8][2][1024]    = 16384

// ---------------------------------------------------------------------------
// shared prologue: h = hbase (+ scale * sum_ks part)  -> rmsnorm -> hn (LDS)
// optionally block(0,0) writes raw h to hout.
// ---------------------------------------------------------------------------
__device__ __forceinline__ void prologue_norm(
    const float* __restrict__ hbase,
    const float* __restrict__ part, int nks, float scale,
    const float* __restrict__ lnw,
    float (*hn)[D], float* red, float* rstd,
    float* __restrict__ hout)
{
  const int t = threadIdx.x;
  const int b = t >> 7;
  const int i0 = (t & 127) * 8;
  float hv[8];
  float ssq = 0.f;
#pragma unroll
  for (int u = 0; u < 8; ++u) {
    const int i = i0 + u;
    float x = hbase[b * D + i];
    if (part != nullptr) {
      float s = 0.f;
      for (int ks = 0; ks < nks; ++ks) s += part[(ks * 2 + b) * D + i];
      x += scale * s;
    }
    hv[u] = x;
    ssq += x * x;
  }
  red[t] = ssq;
  __syncthreads();
  for (int s = 64; s > 0; s >>= 1) {
    if ((t & 127) < s) red[t] += red[t + s];
    __syncthreads();
  }
  if ((t & 127) == 0) rstd[b] = rsqrtf(red[t] * (1.f / D) + 1e-5f);
  __syncthreads();
  const float r = rstd[b];
#pragma unroll
  for (int u = 0; u < 8; ++u) {
    const int i = i0 + u;
    hn[b][i] = hv[u] * r * lnw[i];
  }
  if (hout != nullptr && blockIdx.x == 0 && blockIdx.y == 0) {
#pragma unroll
    for (int u = 0; u < 8; ++u) hout[b * D + i0 + u] = hv[u];
  }
  __syncthreads();
}

// ---------------------------------------------------------------------------
__global__ __launch_bounds__(256) void k_init(const float* __restrict__ embed,
                                              float* __restrict__ h)
{
  const int t = threadIdx.x;
  for (int i = t; i < 2 * D; i += 256) h[i] = embed[i];
}

// ---------------------------------------------------------------------------
// QKV: prologue (combine prev-layer down partials + residual + rmsnorm), then
// GEMV of wq/wk/wv. grid(ks=4, cg=48): mat = cg>>4, jbase=(cg&15)*64,
// K-rows = ks*256..+256 split over 16 kp of 16 rows.
// ---------------------------------------------------------------------------
__global__ __launch_bounds__(256) void k_qkv(
    const float* __restrict__ hbase, const float* __restrict__ down_part,
    float* __restrict__ hout, const float* __restrict__ ln1,
    const float* __restrict__ wq, const float* __restrict__ wk,
    const float* __restrict__ wv,
    float* __restrict__ qkv_part, float scale, int has_prev)
{
  __shared__ float hn[2][D];
  __shared__ float red[256];
  __shared__ float rstd[2];
  __shared__ float redg[16][2][64];
  prologue_norm(hbase, has_prev ? down_part : nullptr, 16, scale, ln1,
                hn, red, rstd, has_prev ? hout : nullptr);
  const int t = threadIdx.x;
  const int ks = blockIdx.x;          // 0..3
  const int cg = blockIdx.y;          // 0..47
  const int mat = cg >> 4;
  const int jbase = (cg & 15) * 64;
  const float* W = (mat == 0) ? wq : (mat == 1) ? wk : wv;
  const int jo4 = (t & 15) * 4;
  const int kp = t >> 4;              // 0..15
  const int ib = ks * 256 + kp * 16;
  float a00=0,a01=0,a02=0,a03=0, a10=0,a11=0,a12=0,a13=0;
#pragma unroll
  for (int r = 0; r < 16; ++r) {
    const int i = ib + r;
    const float4 w = *(const float4*)(W + (size_t)i * D + jbase + jo4);
    const float x0 = hn[0][i], x1 = hn[1][i];
    a00 += w.x * x0; a01 += w.y * x0; a02 += w.z * x0; a03 += w.w * x0;
    a10 += w.x * x1; a11 += w.y * x1; a12 += w.z * x1; a13 += w.w * x1;
  }
  redg[kp][0][jo4+0]=a00; redg[kp][0][jo4+1]=a01; redg[kp][0][jo4+2]=a02; redg[kp][0][jo4+3]=a03;
  redg[kp][1][jo4+0]=a10; redg[kp][1][jo4+1]=a11; redg[kp][1][jo4+2]=a12; redg[kp][1][jo4+3]=a13;
  __syncthreads();
  if (t < 128) {
    const int b = t >> 6, jo = t & 63;
    float s = 0.f;
#pragma unroll
    for (int k2 = 0; k2 < 16; ++k2) s += redg[k2][b][jo];
    qkv_part[((ks * 3 + mat) * 2 + b) * D + jbase + jo] = s;
  }
}

// ---------------------------------------------------------------------------
// Attention, chunked (flash-decoding style). grid(chunk=9, bh=32), 256 thr.
// Chunks 0..7: 64 old cache keys each (also copies cache->out). Chunk 8: the
// new token (combines k/v partials, ropes k, writes slot 512).
// Partials per (b,h,chunk): [m, l, acc[64]] at stride 68.
// ---------------------------------------------------------------------------
__global__ __launch_bounds__(256) void k_attn(
    const float* __restrict__ qkv_part, const int* __restrict__ position,
    const float* __restrict__ k_in, const float* __restrict__ v_in,
    float* __restrict__ k_out, float* __restrict__ v_out,
    float* __restrict__ attn_part)
{
  const int t = threadIdx.x;
  const int chunk = blockIdx.x;   // 0..8
  const int bh = blockIdx.y;      // 0..31
  const int b = bh >> 4, h = bh & 15;
  __shared__ float q[64];
  __shared__ float sc[64];
  __shared__ float red4[4][64];
  __shared__ float pvred[16][64];
  __shared__ float mlsh[2];
  __shared__ float kn[64], vn[64];

  if (t < 64) {
    float s = 0.f;
#pragma unroll
    for (int ks = 0; ks < 4; ++ks)
      s += qkv_part[((ks * 3 + 0) * 2 + b) * D + h * 64 + t];
    q[t] = s;
  }
  __syncthreads();
  if (t < 32) {
    const float pos = (float)position[b];
    const float inv = expf(-(float)t * 0.28782313662425575f); // ln(1e4)/32
    const float ang = pos * inv;
    const float c = cosf(ang), sn = sinf(ang);
    const float x1 = q[t], x2 = q[t + 32];
    q[t]      = (x1 * c - x2 * sn) * 0.125f;   // * 1/sqrt(DH)
    q[t + 32] = (x1 * sn + x2 * c) * 0.125f;
  }
  __syncthreads();

  const size_t row_in  = (size_t)(b * 16 + h) * S_CACHE;
  const size_t row_out = (size_t)(b * 16 + h) * SP1;
  const int pbase = (bh * 9 + chunk) * 68;

  if (chunk < 8) {
    // ---- scores over 64 keys (thread = (kp dims, s_off key)) + K copy ----
    const int s_off = t & 63, kp = t >> 6;
    const int sg = chunk * 64 + s_off;
    const float* krow = k_in + (row_in + sg) * 64;
    float* korow = k_out + (row_out + sg) * 64;
    float dp = 0.f;
#pragma unroll
    for (int c4 = 0; c4 < 4; ++c4) {
      const int d = kp * 16 + c4 * 4;
      const float4 kv = *(const float4*)(krow + d);
      *(float4*)(korow + d) = kv;
      dp += kv.x * q[d] + kv.y * q[d+1] + kv.z * q[d+2] + kv.w * q[d+3];
    }
    red4[kp][s_off] = dp;
    __syncthreads();
    if (t < 64) {
      const float score = red4[0][t] + red4[1][t] + red4[2][t] + red4[3][t];
      float m = score;
      for (int off = 32; off > 0; off >>= 1) m = fmaxf(m, __shfl_xor(m, off));
      const float p = expf(score - m);
      float l = p;
      for (int off = 32; off > 0; off >>= 1) l += __shfl_xor(l, off);
      sc[t] = p;
      if (t == 0) { mlsh[0] = m; mlsh[1] = l; }
    }
    __syncthreads();
    // ---- PV (thread = (sp keys, d4 dims)) + V copy ----
    const int d4 = (t & 15) * 4, sp = t >> 4;
    float ax = 0.f, ay = 0.f, az = 0.f, aw = 0.f;
#pragma unroll
    for (int r = 0; r < 4; ++r) {
      const int sl = sp * 4 + r;
      const int sg2 = chunk * 64 + sl;
      const float* vrow = v_in + (row_in + sg2) * 64;
      const float4 vv = *(const float4*)(vrow + d4);
      *(float4*)(v_out + (row_out + sg2) * 64 + d4) = vv;
      const float p2 = sc[sl];
      ax += vv.x * p2; ay += vv.y * p2; az += vv.z * p2; aw += vv.w * p2;
    }
    pvred[sp][d4+0]=ax; pvred[sp][d4+1]=ay; pvred[sp][d4+2]=az; pvred[sp][d4+3]=aw;
    __syncthreads();
    if (t < 64) {
      float a = 0.f;
#pragma unroll
      for (int s2 = 0; s2 < 16; ++s2) a += pvred[s2][t];
      attn_part[pbase + 2 + t] = a;
      if (t == 0) { attn_part[pbase + 0] = mlsh[0]; attn_part[pbase + 1] = mlsh[1]; }
    }
  } else {
    // ---- new token ----
    if (t < 64) {
      float skv = 0.f, svv = 0.f;
#pragma unroll
      for (int ks = 0; ks < 4; ++ks) {
        skv += qkv_part[((ks * 3 + 1) * 2 + b) * D + h * 64 + t];
        svv += qkv_part[((ks * 3 + 2) * 2 + b) * D + h * 64 + t];
      }
      kn[t] = skv; vn[t] = svv;
    }
    __syncthreads();
    if (t < 32) {
      const float pos = (float)position[b];
      const float inv = expf(-(float)t * 0.28782313662425575f);
      const float ang = pos * inv;
      const float c = cosf(ang), sn = sinf(ang);
      const float x1 = kn[t], x2 = kn[t + 32];
      kn[t]      = x1 * c - x2 * sn;
      kn[t + 32] = x1 * sn + x2 * c;
    }
    __syncthreads();
    if (t < 64) {
      k_out[(row_out + S_CACHE) * 64 + t] = kn[t];
      v_out[(row_out + S_CACHE) * 64 + t] = vn[t];
      float dp = q[t] * kn[t];
      for (int off = 32; off > 0; off >>= 1) dp += __shfl_xor(dp, off);
      attn_part[pbase + 2 + t] = vn[t];
      if (t == 0) { attn_part[pbase + 0] = dp; attn_part[pbase + 1] = 1.f; }
    }
  }
}

// ---------------------------------------------------------------------------
// O-proj: combine attention partials (softmax merge) for this block's K-range,
// then GEMV of wo. grid(ks=8, cg=16); K-range = ks*128..+128 (2 heads).
// ---------------------------------------------------------------------------
__global__ __launch_bounds__(256) void k_oproj(
    const float* __restrict__ attn_part, const float* __restrict__ wo,
    float* __restrict__ oproj_part)
{
  __shared__ float o[2][128];
  __shared__ float cw[2][2][9];
  __shared__ float redg[16][2][64];
  const int t = threadIdx.x;
  const int ks = blockIdx.x;   // 0..7
  const int cg = blockIdx.y;   // 0..15
  const int ibeg = ks * 128;
  const int h0 = ibeg >> 6;
  if (t < 4) {
    const int bb = t >> 1, hr = t & 1;
    const int hh = h0 + hr;
    const int base = ((bb * 16 + hh) * 9) * 68;
    float mg = -1e30f;
    for (int c = 0; c < 9; ++c) mg = fmaxf(mg, attn_part[base + c * 68]);
    float lg = 0.f;
    float wloc[9];
    for (int c = 0; c < 9; ++c) {
      const float w = expf(attn_part[base + c * 68] - mg);
      wloc[c] = w;
      lg += attn_part[base + c * 68 + 1] * w;
    }
    const float invl = 1.f / lg;
    for (int c = 0; c < 9; ++c) cw[bb][hr][c] = wloc[c] * invl;
  }
  __syncthreads();
  {
    const int bb = t >> 7, ir = t & 127;
    const int i = ibeg + ir;
    const int hh = i >> 6, hr = hh - h0, d = i & 63;
    float s = 0.f;
#pragma unroll
    for (int c = 0; c < 9; ++c)
      s += attn_part[((bb * 16 + hh) * 9 + c) * 68 + 2 + d] * cw[bb][hr][c];
    o[bb][ir] = s;
  }
  __syncthreads();
  const int jbase = cg * 64;
  const int jo4 = (t & 15) * 4;
  const int kp = t >> 4;
  const int ib = kp * 8;
  float a00=0,a01=0,a02=0,a03=0, a10=0,a11=0,a12=0,a13=0;
#pragma unroll
  for (int r = 0; r < 8; ++r) {
    const int ir = ib + r;
    const int i = ibeg + ir;
    const float4 w = *(const float4*)(wo + (size_t)i * D + jbase + jo4);
    const float x0 = o[0][ir], x1 = o[1][ir];
    a00 += w.x * x0; a01 += w.y * x0; a02 += w.z * x0; a03 += w.w * x0;
    a10 += w.x * x1; a11 += w.y * x1; a12 += w.z * x1; a13 += w.w * x1;
  }
  redg[kp][0][jo4+0]=a00; redg[kp][0][jo4+1]=a01; redg[kp][0][jo4+2]=a02; redg[kp][0][jo4+3]=a03;
  redg[kp][1][jo4+0]=a10; redg[kp][1][jo4+1]=a11; redg[kp][1][jo4+2]=a12; redg[kp][1][jo4+3]=a13;
  __syncthreads();
  if (t < 128) {
    const int b = t >> 6, jo = t & 63;
    float s = 0.f;
#pragma unroll
    for (int k2 = 0; k2 < 16; ++k2) s += redg[k2][b][jo];
    oproj_part[(ks * 2 + b) * D + jbase + jo] = s;
  }
}

// ---------------------------------------------------------------------------
// Gate+Up: prologue (h2 = h + scale*sum(oproj) , rmsnorm ln2), GEMV of wg+wu.
// grid(ks=4, cg=64). Writes h2 raw via block(0,0).
// ---------------------------------------------------------------------------
__global__ __launch_bounds__(256) void k_gateup(
    const float* __restrict__ hbase, const float* __restrict__ oproj_part,
    float* __restrict__ h2_out, const float* __restrict__ ln2,
    const float* __restrict__ wg, const float* __restrict__ wu,
    float* __restrict__ gu_part, float scale)
{
  __shared__ float hn[2][D];
  __shared__ float red[256];
  __shared__ float rstd[2];
  __shared__ float redg[16][4][64];
  prologue_norm(hbase, oproj_part, 8, scale, ln2, hn, red, rstd, h2_out);
  const int t = threadIdx.x;
  const int ks = blockIdx.x;   // 0..3
  const int cg = blockIdx.y;   // 0..63
  const int jbase = cg * 64;
  const int jo4 = (t & 15) * 4;
  const int kp = t >> 4;
  const int ib = ks * 256 + kp * 16;
  float g00=0,g01=0,g02=0,g03=0, g10=0,g11=0,g12=0,g13=0;
  float u00=0,u01=0,u02=0,u03=0, u10=0,u11=0,u12=0,u13=0;
#pragma unroll
  for (int r = 0; r < 16; ++r) {
    const int i = ib + r;
    const float4 a = *(const float4*)(wg + (size_t)i * DFF + jbase + jo4);
    const float4 c = *(const float4*)(wu + (size_t)i * DFF + jbase + jo4);
    const float x0 = hn[0][i], x1 = hn[1][i];
    g00 += a.x*x0; g01 += a.y*x0; g02 += a.z*x0; g03 += a.w*x0;
    g10 += a.x*x1; g11 += a.y*x1; g12 += a.z*x1; g13 += a.w*x1;
    u00 += c.x*x0; u01 += c.y*x0; u02 += c.z*x0; u03 += c.w*x0;
    u10 += c.x*x1; u11 += c.y*x1; u12 += c.z*x1; u13 += c.w*x1;
  }
  redg[kp][0][jo4+0]=g00; redg[kp][0][jo4+1]=g01; redg[kp][0][jo4+2]=g02; redg[kp][0][jo4+3]=g03;
  redg[kp][1][jo4+0]=g10; redg[kp][1][jo4+1]=g11; redg[kp][1][jo4+2]=g12; redg[kp][1][jo4+3]=g13;
  redg[kp][2][jo4+0]=u00; redg[kp][2][jo4+1]=u01; redg[kp][2][jo4+2]=u02; redg[kp][2][jo4+3]=u03;
  redg[kp][3][jo4+0]=u10; redg[kp][3][jo4+1]=u11; redg[kp][3][jo4+2]=u12; redg[kp][3][jo4+3]=u13;
  __syncthreads();
  {
    const int sel = t >> 6;      // 0:g,b0 1:g,b1 2:u,b0 3:u,b1
    const int jo = t & 63;
    float s = 0.f;
#pragma unroll
    for (int k2 = 0; k2 < 16; ++k2) s += redg[k2][sel][jo];
    const int gm = sel >> 1, b = sel & 1;
    gu_part[((blockIdx.x * 2 + gm) * 2 + b) * DFF + jbase + jo] = s;
  }
}

// ---------------------------------------------------------------------------
// Down: combine g/u partials -> silu(g)*u (K-range), GEMV of wd.
// grid(ks=16, cg=16); K-range = ks*256..+256 of DFF.
// ---------------------------------------------------------------------------
__global__ __launch_bounds__(256) void k_down(
    const float* __restrict__ gu_part, const float* __restrict__ wd,
    float* __restrict__ down_part)
{
  __shared__ float act[2][256];
  __shared__ float redg[16][2][64];
  const int t = threadIdx.x;
  const int ks = blockIdx.x;   // 0..15
  const int cg = blockIdx.y;   // 0..15
  const int ibeg = ks * 256;
#pragma unroll
  for (int u = 0; u < 2; ++u) {
    const int idx = t * 2 + u;
    const int b = idx >> 8, ir = idx & 255;
    const int i = ibeg + ir;
    float g = 0.f, uu = 0.f;
#pragma unroll
    for (int k4 = 0; k4 < 4; ++k4) {
      g  += gu_part[((k4 * 2 + 0) * 2 + b) * DFF + i];
      uu += gu_part[((k4 * 2 + 1) * 2 + b) * DFF + i];
    }
    act[b][ir] = (g / (1.f + expf(-g))) * uu;
  }
  __syncthreads();
  const int jbase = cg * 64;
  const int jo4 = (t & 15) * 4;
  const int kp = t >> 4;
  const int ib = kp * 16;
  float a00=0,a01=0,a02=0,a03=0, a10=0,a11=0,a12=0,a13=0;
#pragma unroll
  for (int r = 0; r < 16; ++r) {
    const int ir = ib + r;
    const int i = ibeg + ir;
    const float4 w = *(const float4*)(wd + (size_t)i * D + jbase + jo4);
    const float x0 = act[0][ir], x1 = act[1][ir];
    a00 += w.x*x0; a01 += w.y*x0; a02 += w.z*x0; a03 += w.w*x0;
    a10 += w.x*x1; a11 += w.y*x1; a12 += w.z*x1; a13 += w.w*x1;
  }
  redg[kp][0][jo4+0]=a00; redg[kp][0][jo4+1]=a01; redg[kp][0][jo4+2]=a02; redg[kp][0][jo4+3]=a03;
  redg[kp][1][jo4+0]=a10; redg[kp][1][jo4+1]=a11; redg[kp][1][jo4+2]=a12; redg[kp][1][jo4+3]=a13;
  __syncthreads();
  if (t < 128) {
    const int b = t >> 6, jo = t & 63;
    float s = 0.f;
#pragma unroll
    for (int k2 = 0; k2 < 16; ++k2) s += redg[k2][b][jo];
    down_part[(ks * 2 + b) * D + jbase + jo] = s;
  }
}

// ---------------------------------------------------------------------------
// Stop-proj GEMV (uses lm_hidden = rmsnorm(h_final, base_norm) via prologue).
// grid(ks=8, cg=16).
// ---------------------------------------------------------------------------
__global__ __launch_bounds__(256) void k_sproj(
    const float* __restrict__ hbase, const float* __restrict__ down_part,
    const float* __restrict__ normw, const float* __restrict__ wsp,
    float* __restrict__ sproj_part, float scale)
{
  __shared__ float hn[2][D];
  __shared__ float red[256];
  __shared__ float rstd[2];
  __shared__ float redg[16][2][64];
  prologue_norm(hbase, down_part, 16, scale, normw, hn, red, rstd, nullptr);
  const int t = threadIdx.x;
  const int ks = blockIdx.x;  // 0..7
  const int cg = blockIdx.y;  // 0..15
  const int jbase = cg * 64;
  const int jo4 = (t & 15) * 4;
  const int kp = t >> 4;
  const int ib = ks * 128 + kp * 8;
  float a00=0,a01=0,a02=0,a03=0, a10=0,a11=0,a12=0,a13=0;
#pragma unroll
  for (int r = 0; r < 8; ++r) {
    const int i = ib + r;
    const float4 w = *(const float4*)(wsp + (size_t)i * D + jbase + jo4);
    const float x0 = hn[0][i], x1 = hn[1][i];
    a00 += w.x*x0; a01 += w.y*x0; a02 += w.z*x0; a03 += w.w*x0;
    a10 += w.x*x1; a11 += w.y*x1; a12 += w.z*x1; a13 += w.w*x1;
  }
  redg[kp][0][jo4+0]=a00; redg[kp][0][jo4+1]=a01; redg[kp][0][jo4+2]=a02; redg[kp][0][jo4+3]=a03;
  redg[kp][1][jo4+0]=a10; redg[kp][1][jo4+1]=a11; redg[kp][1][jo4+2]=a12; redg[kp][1][jo4+3]=a13;
  __syncthreads();
  if (t < 128) {
    const int b = t >> 6, jo = t & 63;
    float s = 0.f;
#pragma unroll
    for (int k2 = 0; k2 < 16; ++k2) s += redg[k2][b][jo];
    sproj_part[(ks * 2 + b) * D + jbase + jo] = s;
  }
}

// ---------------------------------------------------------------------------
// Head: lm_hidden -> FSQ -> lm_fsq (out) and res_in = lm_fsq + embed (ws.h).
// grid(16 blocks); z/zq replicated per block, each block writes 64 columns.
// ---------------------------------------------------------------------------
__global__ __launch_bounds__(256) void k_head1(
    const float* __restrict__ hbase, const float* __restrict__ down_part,
    const float* __restrict__ normw, const float* __restrict__ fsq_in,
    const float* __restrict__ fsq_out, const float* __restrict__ embed,
    float* __restrict__ out_fsq, float* __restrict__ h_res, float scale)
{
  __shared__ float hn[2][D];
  __shared__ float red[256];
  __shared__ float rstd[2];
  __shared__ float zred[4][2][32];
  __shared__ float zq[2][32];
  prologue_norm(hbase, down_part, 16, scale, normw, hn, red, rstd, nullptr);
  const int t = threadIdx.x;
  {
    const int c = t & 31, b = (t >> 5) & 1, kp = t >> 6;
    float s = 0.f;
    for (int i = kp * 256; i < kp * 256 + 256; ++i) s += hn[b][i] * fsq_in[i * 32 + c];
    zred[kp][b][c] = s;
  }
  __syncthreads();
  if (t < 64) {
    const int b = t >> 5, c = t & 31;
    float z = zred[0][b][c] + zred[1][b][c] + zred[2][b][c] + zred[3][b][c];
    z = tanhf(z);
    zq[b][c] = rintf(z * 3.5f) / 3.5f;
  }
  __syncthreads();
  if (t < 128) {
    const int b = t >> 6, jo = t & 63;
    const int j = blockIdx.x * 64 + jo;
    float s = 0.f;
#pragma unroll
    for (int c = 0; c < 32; ++c) s += zq[b][c] * fsq_out[c * D + j];
    out_fsq[b * D + j] = s;
    h_res[b * D + j] = s + embed[b * D + j];
  }
}

// ---------------------------------------------------------------------------
__global__ __launch_bounds__(256) void k_stophead(
    const float* __restrict__ sproj_part, const float* __restrict__ bvec,
    const float* __restrict__ hw, const float* __restrict__ hb,
    float* __restrict__ out_stop)
{
  const int t = threadIdx.x;
  float acc0 = 0.f, acc1 = 0.f;
  for (int j = t; j < D; j += 256) {
    float v0 = bvec[j], v1 = bvec[j];
#pragma unroll
    for (int ks = 0; ks < 8; ++ks) {
      v0 += sproj_part[(ks * 2 + 0) * D + j];
      v1 += sproj_part[(ks * 2 + 1) * D + j];
    }
    acc0 += (v0 / (1.f + expf(-v0))) * hw[j];
    acc1 += (v1 / (1.f + expf(-v1))) * hw[j];
  }
  __shared__ float red[256];
  red[t] = acc0;
  __syncthreads();
  for (int s = 128; s > 0; s >>= 1) { if (t < s) red[t] += red[t + s]; __syncthreads(); }
  if (t == 0) out_stop[0] = red[0] + hb[0];
  __syncthreads();
  red[t] = acc1;
  __syncthreads();
  for (int s = 128; s > 0; s >>= 1) { if (t < s) red[t] += red[t + s]; __syncthreads(); }
  if (t == 0) out_stop[1] = red[0] + hb[0];
}

// ---------------------------------------------------------------------------
__global__ __launch_bounds__(256) void k_final(
    const float* __restrict__ hbase, const float* __restrict__ down_part,
    const float* __restrict__ normw, float* __restrict__ out_rh, float scale)
{
  __shared__ float hn[2][D];
  __shared__ float red[256];
  __shared__ float rstd[2];
  prologue_norm(hbase, down_part, 16, scale, normw, hn, red, rstd, nullptr);
  const int t = threadIdx.x;
  const int b = t >> 7;
  const int i0 = (t & 127) * 8;
#pragma unroll
  for (int u = 0; u < 8; ++u) out_rh[b * D + i0 + u] = hn[b][i0 + u];
}

// ---------------------------------------------------------------------------
extern "C" void kernel_launch(void* const* d_in, const int* in_sizes, int n_in,
                              void* d_out, int out_size, void* d_ws, size_t ws_size,
                              hipStream_t stream) {
  const float* embed      = (const float*)d_in[0];
  const int*   position   = (const int*)d_in[1];
  const float* base_k     = (const float*)d_in[2];
  const float* base_v     = (const float*)d_in[3];
  const float* res_k      = (const float*)d_in[4];
  const float* res_v      = (const float*)d_in[5];
  const float* base_ln1   = (const float*)d_in[6];
  const float* base_ln2   = (const float*)d_in[7];
  const float* base_wq    = (const float*)d_in[8];
  const float* base_wk    = (const float*)d_in[9];
  const float* base_wv    = (const float*)d_in[10];
  const float* base_wo    = (const float*)d_in[11];
  const float* base_wg    = (const float*)d_in[12];
  const float* base_wu    = (const float*)d_in[13];
  const float* base_wd    = (const float*)d_in[14];
  const float* base_norm  = (const float*)d_in[15];
  const float* res_ln1    = (const float*)d_in[16];
  const float* res_ln2    = (const float*)d_in[17];
  const float* res_wq     = (const float*)d_in[18];
  const float* res_wk     = (const float*)d_in[19];
  const float* res_wv     = (const float*)d_in[20];
  const float* res_wo     = (const float*)d_in[21];
  const float* res_wg     = (const float*)d_in[22];
  const float* res_wu     = (const float*)d_in[23];
  const float* res_wd     = (const float*)d_in[24];
  const float* res_norm   = (const float*)d_in[25];
  const float* fsq_in     = (const float*)d_in[26];
  const float* fsq_out    = (const float*)d_in[27];
  const float* stop_proj_w = (const float*)d_in[28];
  const float* stop_proj_b = (const float*)d_in[29];
  const float* stop_head_w = (const float*)d_in[30];
  const float* stop_head_b = (const float*)d_in[31];

  float* out = (float*)d_out;
  float* ws = (float*)d_ws;
  float* W_h     = ws + WS_H;
  float* W_h2    = ws + WS_H2;
  float* W_qkv   = ws + WS_QKV;
  float* W_attn  = ws + WS_ATTN;
  float* W_oproj = ws + WS_OPROJ;
  float* W_gu    = ws + WS_GU;
  float* W_down  = ws + WS_DOWN;
  float* W_sproj = ws + WS_SPROJ;

  const size_t cacheL_in  = (size_t)2 * NHEADS * S_CACHE * DH;   // 1048576
  const size_t cacheL_out = (size_t)2 * NHEADS * SP1 * DH;       // 1050624
  float* out_fsq  = out;
  float* out_rh   = out + 2048;
  float* out_stop = out + 4096;
  float* out_bnk  = out + 4098;
  float* out_bnv  = out_bnk + (size_t)NB_L * cacheL_out;
  float* out_rnk  = out_bnv + (size_t)NB_L * cacheL_out;
  float* out_rnv  = out_rnk + (size_t)NR_L * cacheL_out;

  const float scaleB = 1.4f / sqrtf((float)NB_L);
  const float scaleR = 1.4f / sqrtf((float)NR_L);

  k_init<<<1, 256, 0, stream>>>(embed, W_h);

  auto run_layer = [&](const float* ln1, const float* ln2,
                       const float* wq, const float* wk, const float* wv,
                       const float* wo, const float* wg, const float* wu,
                       const float* wd,
                       const float* kin, const float* vin,
                       float* kout, float* vout,
                       float scale, int has_prev) {
    k_qkv<<<dim3(4, 48), 256, 0, stream>>>(has_prev ? W_h2 : W_h,
                                           has_prev ? W_down : nullptr,
                                           W_h, ln1, wq, wk, wv, W_qkv, scale, has_prev);
    k_attn<<<dim3(9, 32), 256, 0, stream>>>(W_qkv, position, kin, vin, kout, vout, W_attn);
    k_oproj<<<dim3(8, 16), 256, 0, stream>>>(W_attn, wo, W_oproj);
    k_gateup<<<dim3(4, 64), 256, 0, stream>>>(W_h, W_oproj, W_h2, ln2, wg, wu, W_gu, scale);
    k_down<<<dim3(16, 16), 256, 0, stream>>>(W_gu, wd, W_down);
  };

  for (int l = 0; l < NB_L; ++l) {
    run_layer(base_ln1 + (size_t)l * D, base_ln2 + (size_t)l * D,
              base_wq + (size_t)l * D * D, base_wk + (size_t)l * D * D,
              base_wv + (size_t)l * D * D, base_wo + (size_t)l * D * D,
              base_wg + (size_t)l * D * DFF, base_wu + (size_t)l * D * DFF,
              base_wd + (size_t)l * DFF * D,
              base_k + (size_t)l * cacheL_in, base_v + (size_t)l * cacheL_in,
              out_bnk + (size_t)l * cacheL_out, out_bnv + (size_t)l * cacheL_out,
              scaleB, l > 0);
  }

  k_sproj<<<dim3(8, 16), 256, 0, stream>>>(W_h2, W_down, base_norm, stop_proj_w, W_sproj, scaleB);
  k_head1<<<16, 256, 0, stream>>>(W_h2, W_down, base_norm, fsq_in, fsq_out, embed,
                                  out_fsq, W_h, scaleB);
  k_stophead<<<1, 256, 0, stream>>>(W_sproj, stop_proj_b, stop_head_w, stop_head_b, out_stop);

  for (int l = 0; l < NR_L; ++l) {
    run_layer(res_ln1 + (size_t)l * D, res_ln2 + (size_t)l * D,
              res_wq + (size_t)l * D * D, res_wk + (size_t)l * D * D,
              res_wv + (size_t)l * D * D, res_wo + (size_t)l * D * D,
              res_wg + (size_t)l * D * DFF, res_wu + (size_t)l * D * DFF,
              res_wd + (size_t)l * DFF * D,
              res_k + (size_t)l * cacheL_in, res_v + (size_t)l * cacheL_in,
              out_rnk + (size_t)l * cacheL_out, out_rnv + (size_t)l * cacheL_out,
              scaleR, l > 0);
  }

  k_final<<<1, 256, 0, stream>>>(W_h2, W_down, res_norm, out_rh, scaleR);
}

// Round 2
// 1185.176 us; speedup vs baseline: 1.7147x; 1.7147x over previous
//
#include <hip/hip_runtime.h>
#include <cmath>

#define D 1024
#define DFF 4096
#define NHEADS 16
#define DH 64
#define S_CACHE 512
#define SP1 513
#define NB_L 24
#define NR_L 8
#define NCH 17          // 16 data chunks of 32 keys + 1 new-token chunk

// workspace layout (float offsets)
#define WS_H      0         // [2][1024]
#define WS_H2     2048      // [2][1024]
#define WS_QKV    4096      // [16][3][2][1024] = 98304
#define WS_ATTN   102400    // [2][16][17][68]  = 36992
#define WS_OPROJ  139392    // [8][2][1024]     = 16384
#define WS_GU     155776    // [8][2][2][4096]  = 131072
#define WS_DOWN   286848    // [8][2][1024]     = 16384
#define WS_SPROJ  303232    // [8][2][1024]     = 16384

__device__ __forceinline__ float silu(float x) { return x / (1.f + expf(-x)); }

// ---------------------------------------------------------------------------
// prologue: h = hbase (+ scale * sum_ks part) -> rmsnorm(lnw) -> hn (LDS).
// Wave-shuffle reduction: 2 barriers total. block(0,0) optionally writes raw h.
// ---------------------------------------------------------------------------
__device__ __forceinline__ void prologue_norm(
    const float* __restrict__ hbase,
    const float* __restrict__ part, int nks, float scale,
    const float* __restrict__ lnw,
    float (*hn)[D], float* __restrict__ hout)
{
  __shared__ float redw[4];
  const int t = threadIdx.x;
  const int b = t >> 7;
  const int i0 = (t & 127) * 8;
  const float4* hb4 = (const float4*)(hbase + b * D + i0);
  const float4 h0 = hb4[0], h1 = hb4[1];
  float acc[8] = {h0.x, h0.y, h0.z, h0.w, h1.x, h1.y, h1.z, h1.w};
  if (part != nullptr) {
    float s[8] = {0,0,0,0,0,0,0,0};
    for (int ks = 0; ks < nks; ++ks) {
      const float4* p4 = (const float4*)(part + (size_t)(ks * 2 + b) * D + i0);
      const float4 a = p4[0], c = p4[1];
      s[0]+=a.x; s[1]+=a.y; s[2]+=a.z; s[3]+=a.w;
      s[4]+=c.x; s[5]+=c.y; s[6]+=c.z; s[7]+=c.w;
    }
#pragma unroll
    for (int u = 0; u < 8; ++u) acc[u] += scale * s[u];
  }
  float ssq = 0.f;
#pragma unroll
  for (int u = 0; u < 8; ++u) ssq += acc[u] * acc[u];
#pragma unroll
  for (int off = 32; off; off >>= 1) ssq += __shfl_xor(ssq, off);
  if ((t & 63) == 0) redw[t >> 6] = ssq;
  __syncthreads();
  const float r = rsqrtf((redw[b * 2] + redw[b * 2 + 1]) * (1.f / D) + 1e-5f);
#pragma unroll
  for (int u = 0; u < 8; ++u) hn[b][i0 + u] = acc[u] * r * lnw[i0 + u];
  if (hout != nullptr && blockIdx.x == 0 && blockIdx.y == 0) {
    float4* o4 = (float4*)(hout + b * D + i0);
    o4[0] = make_float4(acc[0], acc[1], acc[2], acc[3]);
    o4[1] = make_float4(acc[4], acc[5], acc[6], acc[7]);
  }
  __syncthreads();
}

// ---------------------------------------------------------------------------
// QKV GEMV. grid(16, 48): ks = K-split (64 rows), cg: mat = cg>>4, j-tile 64.
// Weight tile preloaded into regs before prologue (overlap HBM with combine).
// ---------------------------------------------------------------------------
__global__ __launch_bounds__(256) void k_qkv(
    const float* __restrict__ hbase, const float* __restrict__ down_part,
    float* __restrict__ hout, const float* __restrict__ ln1,
    const float* __restrict__ wq, const float* __restrict__ wk,
    const float* __restrict__ wv,
    float* __restrict__ qkv_part, float scale, int has_prev)
{
  __shared__ float hn[2][D];
  __shared__ float redg[16][2][64];
  const int t = threadIdx.x;
  const int ks = blockIdx.x;          // 0..15
  const int cg = blockIdx.y;          // 0..47
  const int mat = cg >> 4;
  const int jbase = (cg & 15) * 64;
  const float* W = (mat == 0) ? wq : (mat == 1) ? wk : wv;
  const int jo4 = (t & 15) * 4;
  const int kp = t >> 4;              // 0..15
  const int ib = ks * 64 + kp * 4;
  float4 wbuf[4];
#pragma unroll
  for (int r = 0; r < 4; ++r)
    wbuf[r] = *(const float4*)(W + (size_t)(ib + r) * D + jbase + jo4);
  prologue_norm(hbase, has_prev ? down_part : nullptr, 8, scale, ln1, hn, hout);
  float a00=0,a01=0,a02=0,a03=0, a10=0,a11=0,a12=0,a13=0;
#pragma unroll
  for (int r = 0; r < 4; ++r) {
    const float x0 = hn[0][ib + r], x1 = hn[1][ib + r];
    a00 += wbuf[r].x*x0; a01 += wbuf[r].y*x0; a02 += wbuf[r].z*x0; a03 += wbuf[r].w*x0;
    a10 += wbuf[r].x*x1; a11 += wbuf[r].y*x1; a12 += wbuf[r].z*x1; a13 += wbuf[r].w*x1;
  }
  redg[kp][0][jo4+0]=a00; redg[kp][0][jo4+1]=a01; redg[kp][0][jo4+2]=a02; redg[kp][0][jo4+3]=a03;
  redg[kp][1][jo4+0]=a10; redg[kp][1][jo4+1]=a11; redg[kp][1][jo4+2]=a12; redg[kp][1][jo4+3]=a13;
  __syncthreads();
  if (t < 128) {
    const int b = t >> 6, jo = t & 63;
    float s = 0.f;
#pragma unroll
    for (int k2 = 0; k2 < 16; ++k2) s += redg[k2][b][jo];
    qkv_part[(size_t)((ks * 3 + mat) * 2 + b) * D + jbase + jo] = s;
  }
}

// ---------------------------------------------------------------------------
// Attention. grid(17, 32): chunks 0..15 = 32 old keys each (+ coalesced cache
// copy); chunk 16 = new token. Partials per (b,h,chunk): [m,l,acc64] stride 68.
// ---------------------------------------------------------------------------
__global__ __launch_bounds__(256) void k_attn(
    const float* __restrict__ qkv_part, const int* __restrict__ position,
    const float* __restrict__ k_in, const float* __restrict__ v_in,
    float* __restrict__ k_out, float* __restrict__ v_out,
    float* __restrict__ attn_part)
{
  const int t = threadIdx.x;
  const int chunk = blockIdx.x;   // 0..16
  const int bh = blockIdx.y;      // 0..31
  const int b = bh >> 4, h = bh & 15;
  __shared__ float q[64];
  __shared__ float sc[32];
  __shared__ float red8[8][32];
  __shared__ float pvred[16][64];
  __shared__ float mlsh[2];
  __shared__ float kn[64], vn[64];
  const size_t row_in  = (size_t)bh * S_CACHE;
  const size_t row_out = (size_t)bh * SP1;
  const int pbase = (bh * NCH + chunk) * 68;

  if (chunk < 16) {
    // coalesced block copy of this chunk's K and V (32 keys x 64 dims each)
    const float4* ksrc = (const float4*)(k_in + (row_in + chunk * 32) * 64);
    float4*       kdst = (float4*)(k_out + (row_out + chunk * 32) * 64);
    const float4* vsrc = (const float4*)(v_in + (row_in + chunk * 32) * 64);
    float4*       vdst = (float4*)(v_out + (row_out + chunk * 32) * 64);
    const float4 kc0 = ksrc[t], kc1 = ksrc[t + 256];
    const float4 vc0 = vsrc[t], vc1 = vsrc[t + 256];
    kdst[t] = kc0; kdst[t + 256] = kc1;
    vdst[t] = vc0; vdst[t + 256] = vc1;
    // q combine + rope
    if (t < 64) {
      float s = 0.f;
#pragma unroll
      for (int ks = 0; ks < 16; ++ks)
        s += qkv_part[(size_t)(ks * 6 + b) * D + h * 64 + t];
      q[t] = s;
    }
    __syncthreads();
    if (t < 32) {
      const float pos = (float)position[b];
      const float inv = expf(-(float)t * 0.28782313662425575f); // ln(1e4)/32
      const float ang = pos * inv;
      const float c = cosf(ang), sn = sinf(ang);
      const float x1 = q[t], x2 = q[t + 32];
      q[t]      = (x1 * c - x2 * sn) * 0.125f;
      q[t + 32] = (x1 * sn + x2 * c) * 0.125f;
    }
    __syncthreads();
    // scores: key = t&31, kp = t>>5 covers dims kp*8..+8 (reads hit L1)
    {
      const int key = t & 31, kp = t >> 5;
      const float* krow = k_in + (row_in + chunk * 32 + key) * 64 + kp * 8;
      const float4 k0 = *(const float4*)krow;
      const float4 k1 = *(const float4*)(krow + 4);
      const int d = kp * 8;
      float dp = k0.x*q[d] + k0.y*q[d+1] + k0.z*q[d+2] + k0.w*q[d+3]
               + k1.x*q[d+4] + k1.y*q[d+5] + k1.z*q[d+6] + k1.w*q[d+7];
      red8[kp][key] = dp;
    }
    __syncthreads();
    if (t < 32) {
      float score = 0.f;
#pragma unroll
      for (int k2 = 0; k2 < 8; ++k2) score += red8[k2][t];
      float m = score;
#pragma unroll
      for (int off = 16; off; off >>= 1) m = fmaxf(m, __shfl_xor(m, off));
      const float p = expf(score - m);
      float l = p;
#pragma unroll
      for (int off = 16; off; off >>= 1) l += __shfl_xor(l, off);
      sc[t] = p;
      if (t == 0) { mlsh[0] = m; mlsh[1] = l; }
    }
    __syncthreads();
    // PV: sp = t>>4 covers 2 keys, d4 = (t&15)*4
    {
      const int d4 = (t & 15) * 4, sp = t >> 4;
      float ax = 0.f, ay = 0.f, az = 0.f, aw = 0.f;
#pragma unroll
      for (int r = 0; r < 2; ++r) {
        const int sl = sp * 2 + r;
        const float4 vv = *(const float4*)(v_in + (row_in + chunk * 32 + sl) * 64 + d4);
        const float p2 = sc[sl];
        ax += vv.x * p2; ay += vv.y * p2; az += vv.z * p2; aw += vv.w * p2;
      }
      pvred[sp][d4+0]=ax; pvred[sp][d4+1]=ay; pvred[sp][d4+2]=az; pvred[sp][d4+3]=aw;
    }
    __syncthreads();
    if (t < 64) {
      float a = 0.f;
#pragma unroll
      for (int s2 = 0; s2 < 16; ++s2) a += pvred[s2][t];
      attn_part[pbase + 2 + t] = a;
      if (t == 0) { attn_part[pbase + 0] = mlsh[0]; attn_part[pbase + 1] = mlsh[1]; }
    }
  } else {
    // new token: combine k/v partials, rope k, write slot 512, emit partial
    if (t < 64) {
      float skv = 0.f, svv = 0.f;
#pragma unroll
      for (int ks = 0; ks < 16; ++ks) {
        skv += qkv_part[(size_t)(ks * 6 + 2 + b) * D + h * 64 + t];
        svv += qkv_part[(size_t)(ks * 6 + 4 + b) * D + h * 64 + t];
      }
      kn[t] = skv; vn[t] = svv;
    }
    if (t < 64) {
      float s = 0.f;
#pragma unroll
      for (int ks = 0; ks < 16; ++ks)
        s += qkv_part[(size_t)(ks * 6 + b) * D + h * 64 + t];
      q[t] = s;
    }
    __syncthreads();
    if (t < 32) {
      const float pos = (float)position[b];
      const float inv = expf(-(float)t * 0.28782313662425575f);
      const float ang = pos * inv;
      const float c = cosf(ang), sn = sinf(ang);
      float x1 = kn[t], x2 = kn[t + 32];
      kn[t]      = x1 * c - x2 * sn;
      kn[t + 32] = x1 * sn + x2 * c;
      x1 = q[t]; x2 = q[t + 32];
      q[t]      = (x1 * c - x2 * sn) * 0.125f;
      q[t + 32] = (x1 * sn + x2 * c) * 0.125f;
    }
    __syncthreads();
    if (t < 64) {
      k_out[(row_out + S_CACHE) * 64 + t] = kn[t];
      v_out[(row_out + S_CACHE) * 64 + t] = vn[t];
      float dp = q[t] * kn[t];
#pragma unroll
      for (int off = 32; off; off >>= 1) dp += __shfl_xor(dp, off);
      attn_part[pbase + 2 + t] = vn[t];
      if (t == 0) { attn_part[pbase + 0] = dp; attn_part[pbase + 1] = 1.f; }
    }
  }
}

// ---------------------------------------------------------------------------
// O-proj. grid(8, 32): ks = 128-row K-range (2 heads), j-tile 32.
// Merges the 17 attention partials (softmax merge), then GEMV of wo.
// ---------------------------------------------------------------------------
__global__ __launch_bounds__(256) void k_oproj(
    const float* __restrict__ attn_part, const float* __restrict__ wo,
    float* __restrict__ oproj_part)
{
  __shared__ float o[2][128];
  __shared__ float cw[2][2][NCH];
  __shared__ float redg[32][2][32];
  const int t = threadIdx.x;
  const int ks = blockIdx.x;   // 0..7
  const int cg = blockIdx.y;   // 0..31
  const int ibeg = ks * 128;
  const int jbase = cg * 32;
  const int jo4 = (t & 7) * 4;
  const int kp = t >> 3;       // 0..31
  float4 wbuf[4];
#pragma unroll
  for (int r = 0; r < 4; ++r)
    wbuf[r] = *(const float4*)(wo + (size_t)(ibeg + kp * 4 + r) * D + jbase + jo4);
  if (t < 4) {
    const int bb = t >> 1, hr = t & 1;
    const int hh = ks * 2 + hr;
    const int base = ((bb * 16 + hh) * NCH) * 68;
    float mg = -1e30f;
    for (int c = 0; c < NCH; ++c) mg = fmaxf(mg, attn_part[base + c * 68]);
    float lg = 0.f;
    float wloc[NCH];
    for (int c = 0; c < NCH; ++c) {
      const float w = expf(attn_part[base + c * 68] - mg);
      wloc[c] = w;
      lg += attn_part[base + c * 68 + 1] * w;
    }
    const float invl = 1.f / lg;
    for (int c = 0; c < NCH; ++c) cw[bb][hr][c] = wloc[c] * invl;
  }
  __syncthreads();
  {
    const int bb = t >> 7, ir = t & 127;
    const int i = ibeg + ir;
    const int hh = i >> 6, hr = hh - ks * 2, d = i & 63;
    float s = 0.f;
#pragma unroll
    for (int c = 0; c < NCH; ++c)
      s += attn_part[((bb * 16 + hh) * NCH + c) * 68 + 2 + d] * cw[bb][hr][c];
    o[bb][ir] = s;
  }
  __syncthreads();
  float a00=0,a01=0,a02=0,a03=0, a10=0,a11=0,a12=0,a13=0;
#pragma unroll
  for (int r = 0; r < 4; ++r) {
    const int ir = kp * 4 + r;
    const float x0 = o[0][ir], x1 = o[1][ir];
    a00 += wbuf[r].x*x0; a01 += wbuf[r].y*x0; a02 += wbuf[r].z*x0; a03 += wbuf[r].w*x0;
    a10 += wbuf[r].x*x1; a11 += wbuf[r].y*x1; a12 += wbuf[r].z*x1; a13 += wbuf[r].w*x1;
  }
  redg[kp][0][jo4+0]=a00; redg[kp][0][jo4+1]=a01; redg[kp][0][jo4+2]=a02; redg[kp][0][jo4+3]=a03;
  redg[kp][1][jo4+0]=a10; redg[kp][1][jo4+1]=a11; redg[kp][1][jo4+2]=a12; redg[kp][1][jo4+3]=a13;
  __syncthreads();
  if (t < 64) {
    const int b = t >> 5, jo = t & 31;
    float s = 0.f;
#pragma unroll
    for (int k2 = 0; k2 < 32; ++k2) s += redg[k2][b][jo];
    oproj_part[(size_t)(ks * 2 + b) * D + jbase + jo] = s;
  }
}

// ---------------------------------------------------------------------------
// Gate+Up GEMV. grid(8, 64): ks = 128-row K-range, j-tile 64.
// ---------------------------------------------------------------------------
__global__ __launch_bounds__(256) void k_gateup(
    const float* __restrict__ hbase, const float* __restrict__ oproj_part,
    float* __restrict__ h2_out, const float* __restrict__ ln2,
    const float* __restrict__ wg, const float* __restrict__ wu,
    float* __restrict__ gu_part, float scale)
{
  __shared__ float hn[2][D];
  __shared__ float redg[16][4][64];
  const int t = threadIdx.x;
  const int ks = blockIdx.x;   // 0..7
  const int cg = blockIdx.y;   // 0..63
  const int jbase = cg * 64;
  const int jo4 = (t & 15) * 4;
  const int kp = t >> 4;
  const int ib = ks * 128 + kp * 8;
  float4 wgb[8];
#pragma unroll
  for (int r = 0; r < 8; ++r)
    wgb[r] = *(const float4*)(wg + (size_t)(ib + r) * DFF + jbase + jo4);
  prologue_norm(hbase, oproj_part, 8, scale, ln2, hn, h2_out);
  float g00=0,g01=0,g02=0,g03=0, g10=0,g11=0,g12=0,g13=0;
  float u00=0,u01=0,u02=0,u03=0, u10=0,u11=0,u12=0,u13=0;
#pragma unroll
  for (int r = 0; r < 8; ++r) {
    const float x0 = hn[0][ib + r], x1 = hn[1][ib + r];
    g00 += wgb[r].x*x0; g01 += wgb[r].y*x0; g02 += wgb[r].z*x0; g03 += wgb[r].w*x0;
    g10 += wgb[r].x*x1; g11 += wgb[r].y*x1; g12 += wgb[r].z*x1; g13 += wgb[r].w*x1;
  }
#pragma unroll
  for (int r = 0; r < 8; ++r) {
    const float4 c = *(const float4*)(wu + (size_t)(ib + r) * DFF + jbase + jo4);
    const float x0 = hn[0][ib + r], x1 = hn[1][ib + r];
    u00 += c.x*x0; u01 += c.y*x0; u02 += c.z*x0; u03 += c.w*x0;
    u10 += c.x*x1; u11 += c.y*x1; u12 += c.z*x1; u13 += c.w*x1;
  }
  redg[kp][0][jo4+0]=g00; redg[kp][0][jo4+1]=g01; redg[kp][0][jo4+2]=g02; redg[kp][0][jo4+3]=g03;
  redg[kp][1][jo4+0]=g10; redg[kp][1][jo4+1]=g11; redg[kp][1][jo4+2]=g12; redg[kp][1][jo4+3]=g13;
  redg[kp][2][jo4+0]=u00; redg[kp][2][jo4+1]=u01; redg[kp][2][jo4+2]=u02; redg[kp][2][jo4+3]=u03;
  redg[kp][3][jo4+0]=u10; redg[kp][3][jo4+1]=u11; redg[kp][3][jo4+2]=u12; redg[kp][3][jo4+3]=u13;
  __syncthreads();
  {
    const int sel = t >> 6;      // 0:g,b0 1:g,b1 2:u,b0 3:u,b1
    const int jo = t & 63;
    float s = 0.f;
#pragma unroll
    for (int k2 = 0; k2 < 16; ++k2) s += redg[k2][sel][jo];
    const int gm = sel >> 1, b = sel & 1;
    gu_part[(size_t)(ks * 4 + gm * 2 + b) * DFF + jbase + jo] = s;
  }
}

// ---------------------------------------------------------------------------
// Down GEMV. grid(8, 32): ks = 512-row K-range of DFF, j-tile 32.
// act = silu(g)*u combined from 8 gu splits.
// ---------------------------------------------------------------------------
__global__ __launch_bounds__(256) void k_down(
    const float* __restrict__ gu_part, const float* __restrict__ wd,
    float* __restrict__ down_part)
{
  __shared__ float act[2][512];
  __shared__ float redg[32][2][32];
  const int t = threadIdx.x;
  const int ks = blockIdx.x;   // 0..7
  const int cg = blockIdx.y;   // 0..31
  const int ibeg = ks * 512;
  const int jbase = cg * 32;
  const int jo4 = (t & 7) * 4;
  const int kp = t >> 3;       // 0..31
  const int ib = kp * 16;
  float4 wbuf[8];
#pragma unroll
  for (int r = 0; r < 8; ++r)
    wbuf[r] = *(const float4*)(wd + (size_t)(ibeg + ib + r) * D + jbase + jo4);
#pragma unroll
  for (int u = 0; u < 4; ++u) {
    const int e = u * 256 + t;
    const int b = e >> 9, ir = e & 511;
    const int i = ibeg + ir;
    float g = 0.f, uu = 0.f;
#pragma unroll
    for (int k = 0; k < 8; ++k) {
      g  += gu_part[(size_t)(k * 4 + b) * DFF + i];
      uu += gu_part[(size_t)(k * 4 + 2 + b) * DFF + i];
    }
    act[b][ir] = silu(g) * uu;
  }
  __syncthreads();
  float a00=0,a01=0,a02=0,a03=0, a10=0,a11=0,a12=0,a13=0;
#pragma unroll
  for (int r = 0; r < 8; ++r) {
    const float x0 = act[0][ib + r], x1 = act[1][ib + r];
    a00 += wbuf[r].x*x0; a01 += wbuf[r].y*x0; a02 += wbuf[r].z*x0; a03 += wbuf[r].w*x0;
    a10 += wbuf[r].x*x1; a11 += wbuf[r].y*x1; a12 += wbuf[r].z*x1; a13 += wbuf[r].w*x1;
  }
#pragma unroll
  for (int r = 8; r < 16; ++r) {
    const float4 w = *(const float4*)(wd + (size_t)(ibeg + ib + r) * D + jbase + jo4);
    const float x0 = act[0][ib + r], x1 = act[1][ib + r];
    a00 += w.x*x0; a01 += w.y*x0; a02 += w.z*x0; a03 += w.w*x0;
    a10 += w.x*x1; a11 += w.y*x1; a12 += w.z*x1; a13 += w.w*x1;
  }
  redg[kp][0][jo4+0]=a00; redg[kp][0][jo4+1]=a01; redg[kp][0][jo4+2]=a02; redg[kp][0][jo4+3]=a03;
  redg[kp][1][jo4+0]=a10; redg[kp][1][jo4+1]=a11; redg[kp][1][jo4+2]=a12; redg[kp][1][jo4+3]=a13;
  __syncthreads();
  if (t < 64) {
    const int b = t >> 5, jo = t & 31;
    float s = 0.f;
#pragma unroll
    for (int k2 = 0; k2 < 32; ++k2) s += redg[k2][b][jo];
    down_part[(size_t)(ks * 2 + b) * D + jbase + jo] = s;
  }
}

// ---------------------------------------------------------------------------
// Fused heads: blocks 0..127 stop-proj GEMV; blocks 128..143 FSQ head.
// Both start from lm_hidden = rmsnorm(h2 + scale*down, base_norm).
// ---------------------------------------------------------------------------
__global__ __launch_bounds__(256) void k_heads(
    const float* __restrict__ hbase, const float* __restrict__ down_part,
    const float* __restrict__ normw, const float* __restrict__ wsp,
    float* __restrict__ sproj_part,
    const float* __restrict__ fsq_in, const float* __restrict__ fsq_out,
    const float* __restrict__ embed,
    float* __restrict__ out_fsq, float* __restrict__ h_res, float scale)
{
  __shared__ float hn[2][D];
  const int t = threadIdx.x;
  const int bid = blockIdx.x;
  if (bid < 128) {
    __shared__ float redg[16][2][64];
    const int ks = bid >> 4, cg = bid & 15;
    const int jbase = cg * 64;
    const int jo4 = (t & 15) * 4;
    const int kp = t >> 4;
    const int ib = ks * 128 + kp * 8;
    float4 wbuf[8];
#pragma unroll
    for (int r = 0; r < 8; ++r)
      wbuf[r] = *(const float4*)(wsp + (size_t)(ib + r) * D + jbase + jo4);
    prologue_norm(hbase, down_part, 8, scale, normw, hn, nullptr);
    float a00=0,a01=0,a02=0,a03=0, a10=0,a11=0,a12=0,a13=0;
#pragma unroll
    for (int r = 0; r < 8; ++r) {
      const float x0 = hn[0][ib + r], x1 = hn[1][ib + r];
      a00 += wbuf[r].x*x0; a01 += wbuf[r].y*x0; a02 += wbuf[r].z*x0; a03 += wbuf[r].w*x0;
      a10 += wbuf[r].x*x1; a11 += wbuf[r].y*x1; a12 += wbuf[r].z*x1; a13 += wbuf[r].w*x1;
    }
    redg[kp][0][jo4+0]=a00; redg[kp][0][jo4+1]=a01; redg[kp][0][jo4+2]=a02; redg[kp][0][jo4+3]=a03;
    redg[kp][1][jo4+0]=a10; redg[kp][1][jo4+1]=a11; redg[kp][1][jo4+2]=a12; redg[kp][1][jo4+3]=a13;
    __syncthreads();
    if (t < 128) {
      const int b = t >> 6, jo = t & 63;
      float s = 0.f;
#pragma unroll
      for (int k2 = 0; k2 < 16; ++k2) s += redg[k2][b][jo];
      sproj_part[(size_t)(ks * 2 + b) * D + jbase + jo] = s;
    }
  } else {
    __shared__ float zred[4][2][32];
    __shared__ float zq[2][32];
    prologue_norm(hbase, down_part, 8, scale, normw, hn, nullptr);
    {
      const int c = t & 31, b = (t >> 5) & 1, kp = t >> 6;
      float s = 0.f;
      for (int i = kp * 256; i < kp * 256 + 256; ++i) s += hn[b][i] * fsq_in[i * 32 + c];
      zred[kp][b][c] = s;
    }
    __syncthreads();
    if (t < 64) {
      const int b = t >> 5, c = t & 31;
      float z = zred[0][b][c] + zred[1][b][c] + zred[2][b][c] + zred[3][b][c];
      z = tanhf(z);
      zq[b][c] = rintf(z * 3.5f) / 3.5f;
    }
    __syncthreads();
    if (t < 128) {
      const int b = t >> 6, jo = t & 63;
      const int j = (bid - 128) * 64 + jo;
      float s = 0.f;
#pragma unroll
      for (int c = 0; c < 32; ++c) s += zq[b][c] * fsq_out[c * D + j];
      out_fsq[b * D + j] = s;
      h_res[b * D + j] = s + embed[b * D + j];
    }
  }
}

// ---------------------------------------------------------------------------
__global__ __launch_bounds__(256) void k_stophead(
    const float* __restrict__ sproj_part, const float* __restrict__ bvec,
    const float* __restrict__ hw, const float* __restrict__ hb,
    float* __restrict__ out_stop)
{
  const int t = threadIdx.x;
  float acc0 = 0.f, acc1 = 0.f;
  for (int j = t; j < D; j += 256) {
    float v0 = bvec[j], v1 = bvec[j];
#pragma unroll
    for (int ks = 0; ks < 8; ++ks) {
      v0 += sproj_part[(ks * 2 + 0) * D + j];
      v1 += sproj_part[(ks * 2 + 1) * D + j];
    }
    acc0 += silu(v0) * hw[j];
    acc1 += silu(v1) * hw[j];
  }
  __shared__ float red[256];
  red[t] = acc0;
  __syncthreads();
  for (int s = 128; s > 0; s >>= 1) { if (t < s) red[t] += red[t + s]; __syncthreads(); }
  if (t == 0) out_stop[0] = red[0] + hb[0];
  __syncthreads();
  red[t] = acc1;
  __syncthreads();
  for (int s = 128; s > 0; s >>= 1) { if (t < s) red[t] += red[t + s]; __syncthreads(); }
  if (t == 0) out_stop[1] = red[0] + hb[0];
}

// ---------------------------------------------------------------------------
__global__ __launch_bounds__(256) void k_final(
    const float* __restrict__ hbase, const float* __restrict__ down_part,
    const float* __restrict__ normw, float* __restrict__ out_rh, float scale)
{
  __shared__ float hn[2][D];
  prologue_norm(hbase, down_part, 8, scale, normw, hn, nullptr);
  const int t = threadIdx.x;
  const int b = t >> 7;
  const int i0 = (t & 127) * 8;
#pragma unroll
  for (int u = 0; u < 8; ++u) out_rh[b * D + i0 + u] = hn[b][i0 + u];
}

// ---------------------------------------------------------------------------
extern "C" void kernel_launch(void* const* d_in, const int* in_sizes, int n_in,
                              void* d_out, int out_size, void* d_ws, size_t ws_size,
                              hipStream_t stream) {
  const float* embed      = (const float*)d_in[0];
  const int*   position   = (const int*)d_in[1];
  const float* base_k     = (const float*)d_in[2];
  const float* base_v     = (const float*)d_in[3];
  const float* res_k      = (const float*)d_in[4];
  const float* res_v      = (const float*)d_in[5];
  const float* base_ln1   = (const float*)d_in[6];
  const float* base_ln2   = (const float*)d_in[7];
  const float* base_wq    = (const float*)d_in[8];
  const float* base_wk    = (const float*)d_in[9];
  const float* base_wv    = (const float*)d_in[10];
  const float* base_wo    = (const float*)d_in[11];
  const float* base_wg    = (const float*)d_in[12];
  const float* base_wu    = (const float*)d_in[13];
  const float* base_wd    = (const float*)d_in[14];
  const float* base_norm  = (const float*)d_in[15];
  const float* res_ln1    = (const float*)d_in[16];
  const float* res_ln2    = (const float*)d_in[17];
  const float* res_wq     = (const float*)d_in[18];
  const float* res_wk     = (const float*)d_in[19];
  const float* res_wv     = (const float*)d_in[20];
  const float* res_wo     = (const float*)d_in[21];
  const float* res_wg     = (const float*)d_in[22];
  const float* res_wu     = (const float*)d_in[23];
  const float* res_wd     = (const float*)d_in[24];
  const float* res_norm   = (const float*)d_in[25];
  const float* fsq_in     = (const float*)d_in[26];
  const float* fsq_out    = (const float*)d_in[27];
  const float* stop_proj_w = (const float*)d_in[28];
  const float* stop_proj_b = (const float*)d_in[29];
  const float* stop_head_w = (const float*)d_in[30];
  const float* stop_head_b = (const float*)d_in[31];

  float* out = (float*)d_out;
  float* ws = (float*)d_ws;
  float* W_h     = ws + WS_H;
  float* W_h2    = ws + WS_H2;
  float* W_qkv   = ws + WS_QKV;
  float* W_attn  = ws + WS_ATTN;
  float* W_oproj = ws + WS_OPROJ;
  float* W_gu    = ws + WS_GU;
  float* W_down  = ws + WS_DOWN;
  float* W_sproj = ws + WS_SPROJ;

  const size_t cacheL_in  = (size_t)2 * NHEADS * S_CACHE * DH;   // 1048576
  const size_t cacheL_out = (size_t)2 * NHEADS * SP1 * DH;       // 1050624
  float* out_fsq  = out;
  float* out_rh   = out + 2048;
  float* out_stop = out + 4096;
  float* out_bnk  = out + 4098;
  float* out_bnv  = out_bnk + (size_t)NB_L * cacheL_out;
  float* out_rnk  = out_bnv + (size_t)NB_L * cacheL_out;
  float* out_rnv  = out_rnk + (size_t)NR_L * cacheL_out;

  const float scaleB = 1.4f / sqrtf((float)NB_L);
  const float scaleR = 1.4f / sqrtf((float)NR_L);

  auto run_layer = [&](const float* hbase, float* hout,
                       const float* ln1, const float* ln2,
                       const float* wq, const float* wk, const float* wv,
                       const float* wo, const float* wg, const float* wu,
                       const float* wd,
                       const float* kin, const float* vin,
                       float* kout, float* vout,
                       float scale, int has_prev) {
    k_qkv<<<dim3(16, 48), 256, 0, stream>>>(hbase, W_down, hout, ln1,
                                            wq, wk, wv, W_qkv, scale, has_prev);
    k_attn<<<dim3(NCH, 32), 256, 0, stream>>>(W_qkv, position, kin, vin, kout, vout, W_attn);
    k_oproj<<<dim3(8, 32), 256, 0, stream>>>(W_attn, wo, W_oproj);
    k_gateup<<<dim3(8, 64), 256, 0, stream>>>(W_h, W_oproj, W_h2, ln2, wg, wu, W_gu, scale);
    k_down<<<dim3(8, 32), 256, 0, stream>>>(W_gu, wd, W_down);
  };

  for (int l = 0; l < NB_L; ++l) {
    run_layer(l == 0 ? embed : W_h2, W_h,
              base_ln1 + (size_t)l * D, base_ln2 + (size_t)l * D,
              base_wq + (size_t)l * D * D, base_wk + (size_t)l * D * D,
              base_wv + (size_t)l * D * D, base_wo + (size_t)l * D * D,
              base_wg + (size_t)l * D * DFF, base_wu + (size_t)l * D * DFF,
              base_wd + (size_t)l * DFF * D,
              base_k + (size_t)l * cacheL_in, base_v + (size_t)l * cacheL_in,
              out_bnk + (size_t)l * cacheL_out, out_bnv + (size_t)l * cacheL_out,
              scaleB, l > 0);
  }

  k_heads<<<144, 256, 0, stream>>>(W_h2, W_down, base_norm, stop_proj_w, W_sproj,
                                   fsq_in, fsq_out, embed, out_fsq, W_h, scaleB);
  k_stophead<<<1, 256, 0, stream>>>(W_sproj, stop_proj_b, stop_head_w, stop_head_b, out_stop);

  for (int l = 0; l < NR_L; ++l) {
    run_layer(l == 0 ? W_h : W_h2, l == 0 ? nullptr : W_h,
              res_ln1 + (size_t)l * D, res_ln2 + (size_t)l * D,
              res_wq + (size_t)l * D * D, res_wk + (size_t)l * D * D,
              res_wv + (size_t)l * D * D, res_wo + (size_t)l * D * D,
              res_wg + (size_t)l * D * DFF, res_wu + (size_t)l * D * DFF,
              res_wd + (size_t)l * DFF * D,
              res_k + (size_t)l * cacheL_in, res_v + (size_t)l * cacheL_in,
              out_rnk + (size_t)l * cacheL_out, out_rnv + (size_t)l * cacheL_out,
              scaleR, l > 0);
  }

  k_final<<<1, 256, 0, stream>>>(W_h2, W_down, res_norm, out_rh, scaleR);
}